// Round 1
// baseline (351.491 us; speedup 1.0000x reference)
//
#include <hip/hip_runtime.h>
#include <math.h>

// Problem constants (fixed by the harness's setup_inputs()).
#define NN      20000
#define IN_DIM  256
#define HID_DIM 256
#define OUT_DIM 128
#define EE      320000
#define GG      64

// Mega-kernel grid: 512 blocks x 256 threads. 2 blocks/CU guaranteed by
// __launch_bounds__(256,2) (VGPR capped at 256, LDS ~1KB) -> all blocks
// co-resident -> software grid barrier is deadlock-free.
#define NB   512
#define GSZ  (NB * 256)
#define SCB  79   // scan blocks: 79*256 = 20224 >= NN

// ---------------------------------------------------------------------------
// Affine collapse (network has no activations):
//   q4 = W4^T lw; q3 = W3^T q4; q2 = W2^T q3; q1 = W1^T q2   (256-vectors)
//   d1 = b1.q2; d2 = b2.q3; d3 = b3.q4; c4 = b4.lw           (scalars)
//   u0 = x.q1;  u_i[c] = sum_{e:col=c} norm_e*(u_{i-1}[row_e] + d_i)
//   out[g] = pool(u4)/maxcnt + lb
//
// Round-10: 9 launches -> 2. All grid-wide dependencies move inside one
// persistent kernel with agent-scope spin barriers (release-arrive /
// relaxed-poll / acquire-complete). CSR entries packed {row,val} as int2 so
// the scatter touches one line per slot and the gather does one 8B load.
// ---------------------------------------------------------------------------

__device__ __forceinline__ float ld_mall(const float* p) {
  return __hip_atomic_load(p, __ATOMIC_RELAXED, __HIP_MEMORY_SCOPE_AGENT);
}

// 256-thread block dot-reduction -> *dst (single writer).
__device__ __forceinline__ void store_reduced(float p, float* dst) {
  __shared__ float red[4];
  int tid = threadIdx.x, lane = tid & 63, w = tid >> 6;
#pragma unroll
  for (int off = 32; off; off >>= 1) p += __shfl_down(p, off);
  if (lane == 0) red[w] = p;
  __syncthreads();
  if (tid == 0) *dst = red[0] + red[1] + red[2] + red[3];
}

// Grid-wide barrier for the persistent mega-kernel. Forward-only counter:
// barrier #phase waits until counter == NB*phase. Thread 0 arrival is an
// agent-scope RELEASE RMW (flushes this XCD's dirty L2 to MALL); completion
// is an agent-scope ACQUIRE load (invalidates L1/L2 so post-barrier plain
// loads see remote writes). __syncthreads drains the block's vmem before
// arrival and propagates the acquire to all threads after.
__device__ __forceinline__ void gbar(int* bar, int phase) {
  __syncthreads();
  if (threadIdx.x == 0) {
    __hip_atomic_fetch_add(bar, 1, __ATOMIC_RELEASE, __HIP_MEMORY_SCOPE_AGENT);
    const int target = NB * phase;
    while (__hip_atomic_load(bar, __ATOMIC_RELAXED, __HIP_MEMORY_SCOPE_AGENT) < target)
      __builtin_amdgcn_s_sleep(1);
    (void)__hip_atomic_load(bar, __ATOMIC_ACQUIRE, __HIP_MEMORY_SCOPE_AGENT);
  }
  __syncthreads();
}

// Launch A: blocks [0,nzb) zero the accumulator zone (deg, ccnt, outsum,
// outcnt, done, bar); blocks [nzb,nzb+256) compute q4[j] = sum_o W4[o,j]*lw[o].
__global__ void k_zero_q4(float4* __restrict__ zp, int n16, int nzb,
                          const float* __restrict__ W4, const float* __restrict__ lw,
                          float* __restrict__ q4) {
  int bid = blockIdx.x, tid = threadIdx.x;
  if (bid < nzb) {
    int i = bid * 256 + tid;
    if (i < n16) zp[i] = make_float4(0.f, 0.f, 0.f, 0.f);
    return;
  }
  int j = bid - nzb;
  float p = (tid < OUT_DIM) ? W4[tid * 256 + j] * lw[tid] : 0.f;
  store_reduced(p, &q4[j]);
}

// One A-application: 4 lanes per node over its CSR segment.
__device__ __forceinline__ void apply_A(const int* __restrict__ cstart,
                                        const int2* __restrict__ sedge,
                                        const float* __restrict__ uin, float d,
                                        float* __restrict__ uout, int gid) {
  int n = gid >> 2, l = gid & 3;
  if (n >= NN) return;
  int s0 = cstart[n], s1 = cstart[n + 1];
  float acc = 0.f, es = 0.f;
  for (int s = s0 + l; s < s1; s += 4) {
    int2 ev = sedge[s];
    float v = __int_as_float(ev.y);
    acc += v * uin[ev.x];
    es  += v;
  }
  acc += __shfl_xor(acc, 1); es += __shfl_xor(es, 1);
  acc += __shfl_xor(acc, 2); es += __shfl_xor(es, 2);
  if (l == 0) uout[n] = acc + d * es;
}

__global__ __launch_bounds__(256, 2) void k_mega(
    const float* __restrict__ x,
    const int* __restrict__ erow, const int* __restrict__ ecol,
    const int* __restrict__ batch,
    const float* __restrict__ W1, const float* __restrict__ b1,
    const float* __restrict__ W2, const float* __restrict__ b2,
    const float* __restrict__ W3, const float* __restrict__ b3,
    const float* __restrict__ b4, const float* __restrict__ lw,
    const float* __restrict__ lb,
    int* __restrict__ deg, int* __restrict__ ccnt,
    int* __restrict__ cstart, int* __restrict__ cursor,
    int2* __restrict__ sedge, int* __restrict__ bsum,
    const float* __restrict__ q4, float* __restrict__ q3,
    float* __restrict__ q2, float* __restrict__ q1, float* __restrict__ dv,
    float* __restrict__ u0, float* __restrict__ u1,
    float* __restrict__ u2, float* __restrict__ u3,
    float* __restrict__ outsum, const float* __restrict__ outcnt_ro,
    float* __restrict__ outcnt, float* __restrict__ out,
    int* __restrict__ done, int* __restrict__ bar) {
  const int bid = blockIdx.x, tid = threadIdx.x;
  const int gid = bid * 256 + tid;
  const int lane = tid & 63, wid = tid >> 6;

  // ---- P1: edge histograms (all blocks) ∥ q3 (blocks 256-511) ----
  for (int e = gid; e < EE; e += GSZ) {
    atomicAdd(&deg[erow[e]], 1);
    atomicAdd(&ccnt[ecol[e]], 1);
  }
  if (bid >= 256) {
    int j = bid - 256;
    float p = W3[tid * 256 + j] * q4[tid];
    store_reduced(p, &q3[j]);
  }
  gbar(bar, 1);

  // ---- P2: scan-local (0-78) ∥ outcnt (79-157) ∥ q2 (158-413) ∥ dots ----
  int my_excl = 0, my_idx = 0;
  if (bid < SCB) {
    my_idx = bid * 256 + tid;
    int v = (my_idx < NN) ? ccnt[my_idx] : 0;
    int incl = v;
#pragma unroll
    for (int off = 1; off < 64; off <<= 1) {
      int t = __shfl_up(incl, off);
      if (lane >= off) incl += t;
    }
    __shared__ int ws2[4];
    if (lane == 63) ws2[wid] = incl;
    __syncthreads();
    int woff = 0;
    for (int j = 0; j < wid; ++j) woff += ws2[j];
    my_excl = woff + incl - v;
    if (tid == 255) bsum[bid] = woff + incl;
  } else if (bid < 158) {
    int n = (bid - SCB) * 256 + tid;
    int b = -1; float cn = 0.f;
    if (n < NN) { b = batch[n]; cn = 1.f; }
#pragma unroll
    for (int off = 1; off < 64; off <<= 1) {
      float c2 = __shfl_up(cn, off);
      int   b2 = __shfl_up(b, off);
      if (lane >= off && b2 == b) cn += c2;
    }
    int bn = __shfl_down(b, 1);
    if (((lane == 63) || (bn != b)) && b >= 0) atomicAdd(&outcnt[b], cn);
  } else if (bid < 414) {
    int j = bid - 158;
    float p = W2[tid * 256 + j] * q3[tid];
    store_reduced(p, &q2[j]);
  } else if (bid == 414) {
    store_reduced(b2[tid] * q3[tid], &dv[1]);
  } else if (bid == 415) {
    store_reduced(b3[tid] * q4[tid], &dv[2]);
  } else if (bid == 416) {
    float p = (tid < OUT_DIM) ? b4[tid] * lw[tid] : 0.f;
    store_reduced(p, &dv[3]);
  }
  gbar(bar, 2);

  // ---- P3: scan-finish (0-78) ∥ q1 (100-355) ∥ d1 (356) ----
  if (bid < SCB) {
    __shared__ int sbs[SCB];
    if (tid < SCB) sbs[tid] = bsum[tid];
    __syncthreads();
    int pref = 0;
    for (int j = 0; j < bid; ++j) pref += sbs[j];
    if (my_idx < NN) {
      int st = pref + my_excl;
      cstart[my_idx] = st;
      cursor[my_idx] = st;
    }
    if (bid == 0 && tid == 0) cstart[NN] = EE;
  } else if (bid >= 100 && bid < 356) {
    int j = bid - 100;
    float p = W1[tid * 256 + j] * q2[tid];
    store_reduced(p, &q1[j]);
  } else if (bid == 356) {
    store_reduced(b1[tid] * q2[tid], &dv[0]);
  }
  gbar(bar, 3);

  // ---- P4: counting-sort scatter (all blocks), then u0 = x.q1 (all) ----
  for (int e = gid; e < EE; e += GSZ) {
    int r = erow[e], c = ecol[e];
    int slot = atomicAdd(&cursor[c], 1);
    float dr = (float)deg[r], dc = (float)deg[c];
    float val = (1.0f / sqrtf(dr)) * (1.0f / sqrtf(dc));  // deg==0 -> inf, as ref
    sedge[slot] = make_int2(r, __float_as_int(val));
  }
  {
    const int gw = gid >> 6;                        // 0..2047 global wave id
    const float4 qv = *(const float4*)(q1 + lane * 4);
#pragma unroll 4
    for (int r = gw; r < NN; r += 2048) {
      const float4 xv = *(const float4*)(x + (size_t)r * IN_DIM + lane * 4);
      float s = xv.x * qv.x + xv.y * qv.y + xv.z * qv.z + xv.w * qv.w;
#pragma unroll
      for (int off = 32; off; off >>= 1) s += __shfl_down(s, off);
      if (lane == 0) u0[r] = s;
    }
  }
  gbar(bar, 4);

  // ---- P5-P7: three A-applications ----
  apply_A(cstart, sedge, u0, dv[0], u1, gid);
  gbar(bar, 5);
  apply_A(cstart, sedge, u1, dv[1], u2, gid);
  gbar(bar, 6);
  apply_A(cstart, sedge, u2, dv[2], u3, gid);
  gbar(bar, 7);

  // ---- P8: last A-application + segmented pool + last-block finalize ----
  {
    int n = gid >> 2, l = gid & 3;
    float pv = 0.f; int b = -1;
    if (n < NN) {
      int s0 = cstart[n], s1 = cstart[n + 1];
      float acc = 0.f, es = 0.f;
      for (int s = s0 + l; s < s1; s += 4) {
        int2 ev = sedge[s];
        float v = __int_as_float(ev.y);
        acc += v * u3[ev.x];
        es  += v;
      }
      acc += __shfl_xor(acc, 1); es += __shfl_xor(es, 1);
      acc += __shfl_xor(acc, 2); es += __shfl_xor(es, 2);
      b = batch[n];
      if (l == 0) pv = acc + dv[3] * es;   // node total on lane l==0 only
    }
#pragma unroll
    for (int off = 1; off < 64; off <<= 1) {
      float s2 = __shfl_up(pv, off);
      int   b2 = __shfl_up(b, off);
      if (lane >= off && b2 == b) pv += s2;
    }
    int bn = __shfl_down(b, 1);
    if (((lane == 63) || (bn != b)) && b >= 0) atomicAdd(&outsum[b], pv);

    // __syncthreads drains this block's vmem (outsum atomics complete at
    // MALL) before thread 0 signals; the LAST block finalizes via
    // MALL-coherent loads (no extra barrier, non-winners just exit).
    __syncthreads();
    __shared__ int winner;
    if (tid == 0) {
      int old = __hip_atomic_fetch_add(done, 1, __ATOMIC_RELAXED, __HIP_MEMORY_SCOPE_AGENT);
      winner = (old == NB - 1) ? 1 : 0;
    }
    __syncthreads();
    if (winner && tid < 64) {
      int g = tid;
      float m = ld_mall(&outcnt_ro[g]);
#pragma unroll
      for (int off = 32; off; off >>= 1) m = fmaxf(m, __shfl_xor(m, off));
      out[g] = ld_mall(&outsum[g]) / m + lb[0];
    }
  }
}

extern "C" void kernel_launch(void* const* d_in, const int* in_sizes, int n_in,
                              void* d_out, int out_size, void* d_ws, size_t ws_size,
                              hipStream_t stream) {
  (void)in_sizes; (void)n_in; (void)out_size; (void)ws_size;
  const float* x     = (const float*)d_in[0];
  const int*   erow  = (const int*)d_in[1];          // edge_index[0,:]
  const int*   ecol  = ((const int*)d_in[1]) + EE;   // edge_index[1,:]
  const int*   batch = (const int*)d_in[2];
  const float* W1 = (const float*)d_in[4];
  const float* b1 = (const float*)d_in[5];
  const float* W2 = (const float*)d_in[6];
  const float* b2 = (const float*)d_in[7];
  const float* W3 = (const float*)d_in[8];
  const float* b3 = (const float*)d_in[9];
  const float* W4 = (const float*)d_in[10];
  const float* b4 = (const float*)d_in[11];
  const float* lw = (const float*)d_in[12];
  const float* lb = (const float*)d_in[13];
  float* out = (float*)d_out;

  // Workspace layout (256-byte aligned slots).
  const size_t PN = 80128;  // 20000*4 rounded up to 256
  char* w = (char*)d_ws;
  // --- zero zone (zeroed by k_zero_q4 blocks) ---
  int*   deg    = (int*)w;    w += PN;
  int*   ccnt   = (int*)w;    w += PN;
  float* outsum = (float*)w;  w += 256;
  float* outcnt = (float*)w;  w += 256;
  int*   done   = (int*)w;    w += 256;
  int*   bar    = (int*)w;    w += 256;
  size_t zero_bytes = (size_t)(w - (char*)d_ws);
  // --- fully-overwritten scratch ---
  int*   cstart = (int*)w;    w += PN + 256;          // NN+1 entries
  int*   cursor = (int*)w;    w += PN;
  int2*  sedge  = (int2*)w;   w += (size_t)EE * 8;    // packed {row, norm}
  int*   bsum   = (int*)w;    w += 512;               // SCB block sums
  float* q4     = (float*)w;  w += 1024;
  float* q3     = (float*)w;  w += 1024;
  float* q2     = (float*)w;  w += 1024;
  float* q1     = (float*)w;  w += 1024;
  float* dv     = (float*)w;  w += 256;
  float* u0     = (float*)w;  w += PN;
  float* u1     = (float*)w;  w += PN;
  float* u2     = (float*)w;  w += PN;
  float* u3     = (float*)w;  w += PN;

  int n16 = (int)(zero_bytes / 16);
  int nzb = (n16 + 255) / 256;

  // Launch A: zero accumulator zone (incl. barrier counter) ∥ q4.
  k_zero_q4<<<nzb + 256, 256, 0, stream>>>((float4*)d_ws, n16, nzb, W4, lw, q4);
  // Launch B: everything else as one persistent grid with 7 spin barriers.
  k_mega<<<NB, 256, 0, stream>>>(x, erow, ecol, batch, W1, b1, W2, b2, W3, b3,
                                 b4, lw, lb, deg, ccnt, cstart, cursor, sedge,
                                 bsum, q4, q3, q2, q1, dv, u0, u1, u2, u3,
                                 outsum, outcnt, outcnt, out, done, bar);
}

// Round 4
// 112.812 us; speedup vs baseline: 3.1157x; 3.1157x over previous
//
#include <hip/hip_runtime.h>
#include <math.h>

// Problem constants (fixed by the harness's setup_inputs()).
#define NN      20000
#define IN_DIM  256
#define HID_DIM 256
#define OUT_DIM 128
#define EE      320000
#define GG      64

#define HQB 313   // hist blocks (1024 thr): 313*1024 >= EE; block 313 = q-chain
#define MVB 1250  // matvec blocks in D2: 1250 * 16 waves = 20000 rows
#define SB  1250  // scatter blocks: 1250*256 == EE exactly
#define GB  313   // gather blocks: 313*256 >= NN*4

// ---------------------------------------------------------------------------
// Affine collapse (network has no activations):
//   q4 = W4^T lw; q3 = W3^T q4; q2 = W2^T q3; q1 = W1^T q2   (256-vectors)
//   d1 = b1.q2; d2 = b2.q3; d3 = b3.q4; c4 = b4.lw           (scalars)
//   u0 = x.q1;  u_i[c] = sum_{e:col=c} norm_e*(u_{i-1}[row_e] + d_i)
//   out[g] = pool(u4)/maxcnt + lb
//
// Round-13: rounds 11/12 (scatter-atomic numerics, fp32 then fp64) both
// failed the harness's numeric gates -> revert to the PROVEN round-9/10
// CSR path verbatim (counting-sort + deterministic 4-lane fp32 gather +
// per-node segmented pooling). Keep only the orthogonal structural wins:
//   - hipMemsetAsync zeroes accumulators (proven graph-capture-safe)
//   - whole q-chain + bias dots fused as ONE block alongside the histogram
//   - the 20.5MB x-matvec hidden under the scan/outcnt launch
// 8 dispatches: memset, hist∥qchain, scan∥cnt∥matvec, scatter, g x3, final.
// ---------------------------------------------------------------------------

__device__ __forceinline__ float ldf_mall(const float* p) {
  return __hip_atomic_load(p, __ATOMIC_RELAXED, __HIP_MEMORY_SCOPE_AGENT);
}

// D1: blocks [0,313) edge histograms; block 313 = full q-chain + bias dots.
__global__ __launch_bounds__(1024) void k_hist_qchain(
    const int* __restrict__ erow, const int* __restrict__ ecol,
    int* __restrict__ deg, int* __restrict__ ccnt,
    const float* __restrict__ W1, const float* __restrict__ b1,
    const float* __restrict__ W2, const float* __restrict__ b2,
    const float* __restrict__ W3, const float* __restrict__ b3,
    const float* __restrict__ W4, const float* __restrict__ b4,
    const float* __restrict__ lw, float* __restrict__ q1g,
    float* __restrict__ dv) {
  const int bid = blockIdx.x, tid = threadIdx.x;

  if (bid < HQB) {
    int e = bid * 1024 + tid;
    if (e < EE) {
      atomicAdd(&deg[erow[e]], 1);
      atomicAdd(&ccnt[ecol[e]], 1);
    }
    return;
  }

  // ---- q-chain block: 4 sequential gemvs, operands staged in LDS ----
  __shared__ float lws[128];
  __shared__ float q4s[256], q3s[256], q2s[256], q1s[256];
  __shared__ float part[16][64][4];
  __shared__ float red[16];
  const int jj = tid & 63, tq = tid >> 6;

  if (tid < 128) lws[tid] = lw[tid];
  __syncthreads();

  // qout[j] = sum_{t<K} W[t*256+j] * qin[t]. Thread (tq,jj) covers outputs
  // 4jj..4jj+3 over t-chunk tq (K/16 rows): float4-coalesced W reads.
  auto gemv = [&](const float* W, const float* qin, float* qout, int K) {
    const int tl = K >> 4, t0 = tq * tl;
    float ax = 0.f, ay = 0.f, az = 0.f, aw = 0.f;
#pragma unroll 8
    for (int t = t0; t < t0 + tl; ++t) {
      const float4 wv = *(const float4*)(W + (size_t)t * 256 + jj * 4);
      const float qv = qin[t];
      ax += wv.x * qv; ay += wv.y * qv; az += wv.z * qv; aw += wv.w * qv;
    }
    part[tq][jj][0] = ax; part[tq][jj][1] = ay;
    part[tq][jj][2] = az; part[tq][jj][3] = aw;
    __syncthreads();
    if (tid < 256) {
      float s = 0.f;
#pragma unroll
      for (int k = 0; k < 16; ++k) s += part[k][tid >> 2][tid & 3];
      qout[tid] = s;
    }
    __syncthreads();
  };

  gemv(W4, lws, q4s, OUT_DIM);   // q4 = W4^T lw   (K = 128)
  gemv(W3, q4s, q3s, HID_DIM);
  gemv(W2, q3s, q2s, HID_DIM);
  gemv(W1, q2s, q1s, HID_DIM);
  if (tid < 256) q1g[tid] = q1s[tid];

  auto dot = [&](const float* a, const float* bl, int K, float* dst) {
    float p = (tid < K) ? a[tid] * bl[tid] : 0.f;
#pragma unroll
    for (int off = 32; off; off >>= 1) p += __shfl_down(p, off);
    if ((tid & 63) == 0) red[tid >> 6] = p;
    __syncthreads();
    if (tid == 0) { float s = 0.f; for (int k = 0; k < 16; ++k) s += red[k]; *dst = s; }
    __syncthreads();
  };
  dot(b1, q2s, HID_DIM, &dv[0]);
  dot(b2, q3s, HID_DIM, &dv[1]);
  dot(b3, q4s, HID_DIM, &dv[2]);
  dot(b4, lws, OUT_DIM, &dv[3]);
}

// D2: block 0 = exclusive scan of ccnt -> cstart/cursor; block 1 = per-graph
// node counts; blocks 2..1251 = u0 = x.q1 (one wave per row, float4 lanes).
__global__ __launch_bounds__(1024) void k_scan_cnt_mv(
    const int* __restrict__ ccnt, int* __restrict__ cstart, int* __restrict__ cursor,
    const int* __restrict__ batch, float* __restrict__ outcnt,
    const float* __restrict__ x, const float* __restrict__ q1,
    float* __restrict__ u0) {
  int bid = blockIdx.x, tid = threadIdx.x, lane = tid & 63, wid = tid >> 6;

  if (bid == 0) {  // exclusive scan (verbatim proven code)
    __shared__ int ws[16];
    const int PER = 20;            // 1024*20 = 20480 >= NN
    int base = tid * PER;
    int v[PER]; int sum = 0;
#pragma unroll
    for (int i = 0; i < PER; ++i) { int idx = base + i; v[i] = (idx < NN) ? ccnt[idx] : 0; sum += v[i]; }
    int incl = sum;
#pragma unroll
    for (int off = 1; off < 64; off <<= 1) { int t = __shfl_up(incl, off); if (lane >= off) incl += t; }
    if (lane == 63) ws[wid] = incl;
    __syncthreads();
    if (tid == 0) { int r = 0; for (int j = 0; j < 16; ++j) { int t = ws[j]; ws[j] = r; r += t; } }
    __syncthreads();
    int run = ws[wid] + incl - sum;
#pragma unroll
    for (int i = 0; i < PER; ++i) {
      int idx = base + i;
      if (idx < NN) { cstart[idx] = run; cursor[idx] = run; }
      run += v[i];
    }
    if (tid == 1023) cstart[NN] = run;   // == EE
    return;
  }

  if (bid == 1) {  // per-graph node counts (verbatim proven code)
    for (int base = 0; base < NN; base += 1024) {
      int n = base + tid;
      int b = -1; float cn = 0.f;
      if (n < NN) { b = batch[n]; cn = 1.f; }
#pragma unroll
      for (int off = 1; off < 64; off <<= 1) {
        float c2 = __shfl_up(cn, off);
        int   b2 = __shfl_up(b, off);
        if (lane >= off && b2 == b) cn += c2;
      }
      int bn = __shfl_down(b, 1);
      if (((lane == 63) || (bn != b)) && b >= 0) atomicAdd(&outcnt[b], cn);
    }
    return;
  }

  // matvec: wave w of block handles row (bid-2)*16 + w.
  int r = (bid - 2) * 16 + wid;
  if (r >= NN) return;
  const float4 xv = *(const float4*)(x + (size_t)r * IN_DIM + lane * 4);
  const float4 qv = *(const float4*)(q1 + lane * 4);
  float s = xv.x * qv.x + xv.y * qv.y + xv.z * qv.z + xv.w * qv.w;
#pragma unroll
  for (int off = 32; off; off >>= 1) s += __shfl_down(s, off);
  if (lane == 0) u0[r] = s;
}

// D3: counting-sort CSR scatter (fused norm), int2-packed {row, val}.
__global__ __launch_bounds__(256) void k_scatter(
    const int* __restrict__ erow, const int* __restrict__ ecol,
    const int* __restrict__ deg, int* __restrict__ cursor,
    int2* __restrict__ sedge) {
  int e = blockIdx.x * 256 + threadIdx.x;   // grid = 1250, exact
  int r = erow[e], c = ecol[e];
  int slot = atomicAdd(&cursor[c], 1);
  float dr = (float)deg[r], dc = (float)deg[c];
  float val = (1.0f / sqrtf(dr)) * (1.0f / sqrtf(dc));  // deg==0 -> inf, as ref
  sedge[slot] = make_int2(r, __float_as_int(val));
}

// D4-D6: atomic-free A-application, 4 lanes per node (proven verbatim).
__global__ __launch_bounds__(256) void k_gather(
    const int* __restrict__ cstart, const int2* __restrict__ sedge,
    const float* __restrict__ uin, const float* __restrict__ dptr,
    float* __restrict__ uout) {
  int gid = blockIdx.x * 256 + threadIdx.x;
  int n = gid >> 2, l = gid & 3;
  if (n >= NN) return;
  int s0 = cstart[n], s1 = cstart[n + 1];
  float acc = 0.f, es = 0.f;
  for (int s = s0 + l; s < s1; s += 4) {
    int2 ev = sedge[s];
    float v = __int_as_float(ev.y);
    acc += v * uin[ev.x];
    es  += v;
  }
  acc += __shfl_xor(acc, 1); es += __shfl_xor(es, 1);
  acc += __shfl_xor(acc, 2); es += __shfl_xor(es, 2);
  if (l == 0) uout[n] = acc + dptr[0] * es;
}

// D7: last A-application + segmented per-node pool + last-block finalize.
__global__ __launch_bounds__(256) void k_gather_pool_final(
    const int* __restrict__ cstart, const int2* __restrict__ sedge,
    const float* __restrict__ uin, const float* __restrict__ dptr,
    const int* __restrict__ batch, float* __restrict__ outsum,
    const float* __restrict__ outcnt, const float* __restrict__ lb,
    float* __restrict__ out, int* __restrict__ done, int nblocks) {
  int gid = blockIdx.x * 256 + threadIdx.x;
  int lane = threadIdx.x & 63;
  int n = gid >> 2, l = gid & 3;
  float pv = 0.f; int b = -1;
  if (n < NN) {
    int s0 = cstart[n], s1 = cstart[n + 1];
    float acc = 0.f, es = 0.f;
    for (int s = s0 + l; s < s1; s += 4) {
      int2 ev = sedge[s];
      float v = __int_as_float(ev.y);
      acc += v * uin[ev.x];
      es  += v;
    }
    acc += __shfl_xor(acc, 1); es += __shfl_xor(es, 1);
    acc += __shfl_xor(acc, 2); es += __shfl_xor(es, 2);
    b = batch[n];
    if (l == 0) pv = acc + dptr[0] * es;   // node total on lane l==0 only
  }
#pragma unroll
  for (int off = 1; off < 64; off <<= 1) {
    float s2 = __shfl_up(pv, off);
    int   b2 = __shfl_up(b, off);
    if (lane >= off && b2 == b) pv += s2;
  }
  int bn = __shfl_down(b, 1);
  if (((lane == 63) || (bn != b)) && b >= 0) atomicAdd(&outsum[b], pv);

  // __syncthreads drains this block's vmem (outsum atomics complete at MALL)
  // before thread 0 signals; the LAST block to signal finalizes, reading
  // outsum/outcnt through MALL-coherent loads (proven pattern).
  __syncthreads();
  __shared__ int winner;
  if (threadIdx.x == 0) {
    int old = __hip_atomic_fetch_add(done, 1, __ATOMIC_RELAXED, __HIP_MEMORY_SCOPE_AGENT);
    winner = (old == nblocks - 1) ? 1 : 0;
  }
  __syncthreads();
  if (winner && threadIdx.x < GG) {
    int g = threadIdx.x;
    float m = ldf_mall(&outcnt[g]);
#pragma unroll
    for (int off = 32; off; off >>= 1) m = fmaxf(m, __shfl_xor(m, off));
    out[g] = ldf_mall(&outsum[g]) / m + lb[0];
  }
}

extern "C" void kernel_launch(void* const* d_in, const int* in_sizes, int n_in,
                              void* d_out, int out_size, void* d_ws, size_t ws_size,
                              hipStream_t stream) {
  (void)in_sizes; (void)n_in; (void)out_size; (void)ws_size;
  const float* x     = (const float*)d_in[0];
  const int*   erow  = (const int*)d_in[1];          // edge_index[0,:]
  const int*   ecol  = ((const int*)d_in[1]) + EE;   // edge_index[1,:]
  const int*   batch = (const int*)d_in[2];
  const float* W1 = (const float*)d_in[4];
  const float* b1 = (const float*)d_in[5];
  const float* W2 = (const float*)d_in[6];
  const float* b2 = (const float*)d_in[7];
  const float* W3 = (const float*)d_in[8];
  const float* b3 = (const float*)d_in[9];
  const float* W4 = (const float*)d_in[10];
  const float* b4 = (const float*)d_in[11];
  const float* lw = (const float*)d_in[12];
  const float* lb = (const float*)d_in[13];
  float* out = (float*)d_out;

  // Workspace layout (256-byte aligned slots).
  const size_t PN = 80128;  // 20000*4 rounded up to 256
  char* w = (char*)d_ws;
  // --- memset zone ---
  int*   deg    = (int*)w;    w += PN;
  int*   ccnt   = (int*)w;    w += PN;
  float* outsum = (float*)w;  w += 256;
  float* outcnt = (float*)w;  w += 256;
  int*   done   = (int*)w;    w += 256;
  size_t zbytes = (size_t)(w - (char*)d_ws);
  // --- fully-overwritten scratch ---
  int*   cstart = (int*)w;    w += PN + 256;          // NN+1 entries
  int*   cursor = (int*)w;    w += PN;
  int2*  sedge  = (int2*)w;   w += (size_t)EE * 8;    // packed {row, norm}
  float* q1     = (float*)w;  w += 1024;
  float* dv     = (float*)w;  w += 256;
  float* u0     = (float*)w;  w += PN;
  float* u1     = (float*)w;  w += PN;
  float* u2     = (float*)w;  w += PN;
  float* u3     = (float*)w;  w += PN;

  // D0: zero accumulators (stream-ordered, graph-capture-safe).
  hipMemsetAsync(d_ws, 0, zbytes, stream);
  // D1: edge histograms ∥ full q-chain + bias dots.
  k_hist_qchain<<<HQB + 1, 1024, 0, stream>>>(erow, ecol, deg, ccnt,
                                              W1, b1, W2, b2, W3, b3, W4, b4,
                                              lw, q1, dv);
  // D2: scan ∥ graph counts ∥ u0 = x.q1.
  k_scan_cnt_mv<<<2 + MVB, 1024, 0, stream>>>(ccnt, cstart, cursor, batch,
                                              outcnt, x, q1, u0);
  // D3: CSR counting-sort scatter.
  k_scatter<<<SB, 256, 0, stream>>>(erow, ecol, deg, cursor, sedge);
  // D4-D6: three A-applications.
  k_gather<<<GB, 256, 0, stream>>>(cstart, sedge, u0, dv + 0, u1);
  k_gather<<<GB, 256, 0, stream>>>(cstart, sedge, u1, dv + 1, u2);
  k_gather<<<GB, 256, 0, stream>>>(cstart, sedge, u2, dv + 2, u3);
  // D7: last application + per-node pool + last-block finalize.
  k_gather_pool_final<<<GB, 256, 0, stream>>>(cstart, sedge, u3, dv + 3, batch,
                                              outsum, outcnt, lb, out, done, GB);
}